// Round 1
// baseline (902.321 us; speedup 1.0000x reference)
//
#include <hip/hip_runtime.h>
#include <math.h>

#define N_IMG 2
#define A_ 9
#define C_ 80
#define H_ 100
#define W_ 152
#define HW_ (H_*W_)            // 15200
#define L_ (HW_*A_)            // 136800
#define ACH 720                // A*C channels of box_cls
#define RCH 36                 // A*4 channels of box_regression
#define ELEMS (ACH*HW_)        // 10,944,000 per image
#define TOTAL (N_IMG*ELEMS)    // 21,888,000
#define CAP 16384
#define K_ 1000
#define OUT_TOP 100
#define XTHRESH (-0.6f)
#define CLIPV 4.135166556742356f
#define NMS_T 0.5f

// ws layout:
//   [0, 8)        : u32 cnt[2]
//   [64, 16064)   : u64 topk[2][1000]
//   [16384, ...)  : u64 cand[2][CAP]

__device__ __forceinline__ unsigned int orderable(unsigned int b) {
    return (b & 0x80000000u) ? ~b : (b | 0x80000000u);
}

__global__ void collect_kernel(const float* __restrict__ cls,
                               unsigned long long* __restrict__ cand,
                               unsigned int* __restrict__ cnt) {
    const int nvec = TOTAL / 4;
    for (int v = blockIdx.x * blockDim.x + threadIdx.x; v < nvec;
         v += gridDim.x * blockDim.x) {
        float4 f = ((const float4*)cls)[v];
        float xs[4] = {f.x, f.y, f.z, f.w};
        #pragma unroll
        for (int k = 0; k < 4; ++k) {
            float x = xs[k];
            if (x > XTHRESH) {
                int lin = v * 4 + k;
                int n   = lin / ELEMS;
                int rem = lin - n * ELEMS;
                int ch  = rem / HW_;
                int pix = rem - ch * HW_;
                int a   = ch / C_;
                int c   = ch - a * C_;
                unsigned int flat = (unsigned int)((pix * A_ + a) * C_ + c);
                unsigned int u = orderable(__float_as_uint(x));
                unsigned int pos = atomicAdd(&cnt[n], 1u);
                if (pos < CAP)
                    cand[(size_t)n * CAP + pos] =
                        ((unsigned long long)u << 32) | (unsigned long long)(~flat);
            }
        }
    }
}

#define CHUNK 2048
__global__ void select_kernel(const unsigned long long* __restrict__ cand,
                              const unsigned int* __restrict__ cnt,
                              unsigned long long* __restrict__ topk) {
    int img = blockIdx.y;
    int M = (int)min(cnt[img], (unsigned int)CAP);
    if ((int)(blockIdx.x * blockDim.x) >= M) return;
    int g = blockIdx.x * blockDim.x + threadIdx.x;
    __shared__ unsigned long long sk[CHUNK];
    unsigned long long mykey = (g < M) ? cand[(size_t)img * CAP + g] : 0ull;
    int rank = 0;
    for (int base = 0; base < M; base += CHUNK) {
        int cn = min(CHUNK, M - base);
        __syncthreads();
        for (int t = threadIdx.x; t < cn; t += blockDim.x)
            sk[t] = cand[(size_t)img * CAP + base + t];
        __syncthreads();
        if (g < M)
            for (int t = 0; t < cn; ++t) rank += (sk[t] > mykey);
    }
    if (g < M && rank < K_) topk[img * K_ + rank] = mykey;
}

__global__ __launch_bounds__(1024)
void decode_nms_kernel(const float* __restrict__ reg,
                       const float* __restrict__ anchors,
                       const unsigned long long* __restrict__ topk,
                       float* __restrict__ out) {
    const int img = blockIdx.x;
    __shared__ float bx1[K_], by1[K_], bx2[K_], by2[K_];
    __shared__ float ox1[K_], oy1[K_], ox2[K_], oy2[K_];
    __shared__ float areaS[K_], scS[K_];
    __shared__ int clsS[K_];
    __shared__ unsigned long long maskL[64][16];
    __shared__ unsigned long long keepw[16];
    __shared__ int totkeep;

    int i = threadIdx.x;
    if (i < K_) {
        unsigned long long key = topk[img * K_ + i];
        float score = -1.0f, x1 = 0, y1 = 0, x2 = 0, y2 = 0;
        int clsv = 0;
        if (key != 0ull) {
            unsigned int u = (unsigned int)(key >> 32);
            unsigned int flat = ~((unsigned int)key);
            unsigned int b = (u & 0x80000000u) ? (u & 0x7fffffffu) : ~u;
            float x = __uint_as_float(b);
            score = (float)(1.0 / (1.0 + exp(-(double)x)));
            int loc = flat / C_;
            clsv = (int)(flat - (unsigned)loc * C_) + 1;
            int a = loc % A_;
            int pix = loc / A_;
            int h = pix / W_;
            int w = pix - h * W_;
            float a0 = anchors[loc * 4 + 0], a1 = anchors[loc * 4 + 1];
            float a2 = anchors[loc * 4 + 2], a3 = anchors[loc * 4 + 3];
            int rbase = ((img * RCH + a * 4) * H_ + h) * W_ + w;
            float r0 = reg[rbase], r1 = reg[rbase + HW_];
            float r2 = reg[rbase + 2 * HW_], r3 = reg[rbase + 3 * HW_];
            float wA = a2 - a0 + 1.0f, hA = a3 - a1 + 1.0f;
            float cx = a0 + 0.5f * wA, cy = a1 + 0.5f * hA;
            float dx = r0 / 10.0f, dy = r1 / 10.0f;
            float dw = fminf(r2 / 5.0f, CLIPV), dh = fminf(r3 / 5.0f, CLIPV);
            float pcx = dx * wA + cx, pcy = dy * hA + cy;
            float pw = expf(dw) * wA, ph = expf(dh) * hA;
            x1 = pcx - 0.5f * pw;
            y1 = pcy - 0.5f * ph;
            x2 = pcx + 0.5f * pw - 1.0f;
            y2 = pcy + 0.5f * ph - 1.0f;
            x1 = fminf(fmaxf(x1, 0.0f), 1215.0f);
            y1 = fminf(fmaxf(y1, 0.0f), 799.0f);
            x2 = fminf(fmaxf(x2, 0.0f), 1215.0f);
            y2 = fminf(fmaxf(y2, 0.0f), 799.0f);
            bool ks = (x2 - x1 + 1.0f >= 0.0f) && (y2 - y1 + 1.0f >= 0.0f);
            if (!ks) score = -1.0f;
        }
        bx1[i] = x1; by1[i] = y1; bx2[i] = x2; by2[i] = y2;
        float off = (float)clsv * 1218.0f;
        float o0 = x1 + off, o1 = y1 + off, o2 = x2 + off, o3 = y2 + off;
        ox1[i] = o0; oy1[i] = o1; ox2[i] = o2; oy2[i] = o3;
        areaS[i] = (o2 - o0 + 1.0f) * (o3 - o1 + 1.0f);
        scS[i] = score;
        clsS[i] = clsv;
    }
    __syncthreads();

    // greedy NMS: remv bitmask lives in wave-0 lanes 0..15
    unsigned long long remv = 0ull;
    if (threadIdx.x < 16) {
        unsigned long long r = 0ull;
        for (int t = 0; t < 64; ++t) {
            int idx = (int)threadIdx.x * 64 + t;
            if (idx >= K_ || scS[idx] < 0.0f) r |= (1ull << t);
        }
        remv = r;
    }
    for (int c = 0; c < 16; ++c) {
        int r = threadIdx.x >> 4;      // 0..63 row within chunk
        int wd = threadIdx.x & 15;     // 0..15 word
        int ii = c * 64 + r;
        unsigned long long m = 0ull;
        if (ii < K_) {
            float ax1 = ox1[ii], ay1 = oy1[ii], ax2 = ox2[ii], ay2 = oy2[ii];
            float aar = areaS[ii];
            int jbase = wd * 64;
            for (int jj = 0; jj < 64; ++jj) {
                int j = jbase + jj;
                if (j > ii && j < K_) {
                    float ix1 = fmaxf(ax1, ox1[j]);
                    float iy1 = fmaxf(ay1, oy1[j]);
                    float ix2 = fminf(ax2, ox2[j]);
                    float iy2 = fminf(ay2, oy2[j]);
                    float iw = fmaxf(ix2 - ix1 + 1.0f, 0.0f);
                    float ih = fmaxf(iy2 - iy1 + 1.0f, 0.0f);
                    float inter = iw * ih;
                    float iou = inter / (aar + areaS[j] - inter);
                    if (iou > NMS_T) m |= (1ull << jj);
                }
            }
        }
        maskL[r][wd] = m;
        __syncthreads();
        if (threadIdx.x < 64) {
            for (int rr = 0; rr < 64; ++rr) {
                int iidx = c * 64 + rr;
                unsigned long long wv = __shfl(remv, c, 64);
                bool alive = (iidx < K_) && !((wv >> rr) & 1ull);
                if (alive && threadIdx.x < 16) remv |= maskL[rr][threadIdx.x];
            }
        }
        __syncthreads();
    }
    if (threadIdx.x < 16) keepw[threadIdx.x] = ~remv;
    __syncthreads();
    if (threadIdx.x == 0) {
        int t = 0;
        for (int wv = 0; wv < 16; ++wv) t += __popcll(keepw[wv]);
        totkeep = t;
    }
    __syncthreads();

    if (i < K_) {
        int wv = i >> 6, bt = i & 63;
        bool kept = (keepw[wv] >> bt) & 1ull;
        int pre = 0;
        for (int t = 0; t < wv; ++t) pre += __popcll(keepw[t]);
        if (bt) pre += __popcll(keepw[wv] & ((~0ull) >> (64 - bt)));
        int slot = -1;
        float outsc = -1.0f;
        if (kept) {
            if (pre < OUT_TOP) slot = pre;
            outsc = scS[i];
        } else {
            int s = totkeep + (i - pre);
            if (s < OUT_TOP) slot = s;
        }
        if (slot >= 0) {
            float* ob = out + (size_t)img * OUT_TOP * 4;
            ob[slot * 4 + 0] = bx1[i];
            ob[slot * 4 + 1] = by1[i];
            ob[slot * 4 + 2] = bx2[i];
            ob[slot * 4 + 3] = by2[i];
            out[N_IMG * OUT_TOP * 4 + img * OUT_TOP + slot] = outsc;
            out[N_IMG * OUT_TOP * 5 + img * OUT_TOP + slot] = (float)clsS[i];
        }
    }
}

extern "C" void kernel_launch(void* const* d_in, const int* in_sizes, int n_in,
                              void* d_out, int out_size, void* d_ws, size_t ws_size,
                              hipStream_t stream) {
    const float* box_cls = (const float*)d_in[0];
    const float* box_reg = (const float*)d_in[1];
    const float* anchors = (const float*)d_in[2];
    float* out = (float*)d_out;

    unsigned int* cnt = (unsigned int*)d_ws;
    unsigned long long* topk = (unsigned long long*)((char*)d_ws + 64);
    unsigned long long* cand = (unsigned long long*)((char*)d_ws + 16384);

    hipMemsetAsync(d_ws, 0, 16384, stream);
    hipLaunchKernelGGL(collect_kernel, dim3(2048), dim3(256), 0, stream,
                       box_cls, cand, cnt);
    hipLaunchKernelGGL(select_kernel, dim3(CAP / 256, N_IMG), dim3(256), 0, stream,
                       cand, cnt, topk);
    hipLaunchKernelGGL(decode_nms_kernel, dim3(N_IMG), dim3(1024), 0, stream,
                       box_reg, anchors, topk, out);
}

// Round 3
// 379.932 us; speedup vs baseline: 2.3750x; 2.3750x over previous
//
#include <hip/hip_runtime.h>
#include <math.h>

#define N_IMG 2
#define A_ 9
#define C_ 80
#define H_ 100
#define W_ 152
#define HW_ (H_*W_)            // 15200
#define ACH 720                // A*C channels of box_cls
#define RCH 36                 // A*4 channels of box_regression
#define ELEMS (ACH*HW_)        // 10,944,000 per image
#define TOTAL (N_IMG*ELEMS)    // 21,888,000
#define CAP 6144
#define K_ 1000
#define OUT_TOP 100
#define XTHRESH (-0.6f)
#define CLIPV 4.135166556742356f
#define NMS_T 0.5f
#define MWORDS 8704            // triangular mask u64 words per image

// ws layout (bytes):
//   [0,64)          u32 cnt[2]
//   [64,32064)      float4 obox[2][1000]   (offset boxes)
//   [32064,64064)   float4 bbox[2][1000]   (clipped boxes)
//   [64064,72064)   float  sc[2][1000]
//   [72064,80064)   float  cls[2][1000]
//   [80064,96448)   u64    tdiag[2][1024]  (transposed diagonal tiles)
//   [96448,...)     union { u64 cand[2][CAP] (98KB, dead after select)
//                           u64 maskT[2][MWORDS] (139KB) }   total 235,712 B
#define WS_OBOX 64
#define WS_BBOX 32064
#define WS_SC   64064
#define WS_CLS  72064
#define WS_TD   80064
#define WS_MASK 96448
#define WS_CAND 96448

__device__ __forceinline__ unsigned int orderable(unsigned int b) {
    return (b & 0x80000000u) ? ~b : (b | 0x80000000u);
}

__global__ void init_kernel(unsigned int* __restrict__ cnt,
                            float4* __restrict__ oboxg,
                            float4* __restrict__ bboxg,
                            float* __restrict__ scg,
                            float* __restrict__ clsg) {
    const int img = blockIdx.x;
    const int i = threadIdx.x;
    if (img == 0 && i < 2) cnt[i] = 0u;
    if (i < K_) {
        oboxg[img*K_ + i] = make_float4(0.f, 0.f, 0.f, 0.f);
        bboxg[img*K_ + i] = make_float4(0.f, 0.f, 0.f, 0.f);
        scg[img*K_ + i] = -1.0f;
        clsg[img*K_ + i] = 0.0f;
    }
}

__global__ void collect_kernel(const float* __restrict__ cls,
                               unsigned long long* __restrict__ cand,
                               unsigned int* __restrict__ cnt) {
    const int nvec = TOTAL / 4;
    for (int v = blockIdx.x * blockDim.x + threadIdx.x; v < nvec;
         v += gridDim.x * blockDim.x) {
        float4 f = ((const float4*)cls)[v];
        float xs[4] = {f.x, f.y, f.z, f.w};
        #pragma unroll
        for (int k = 0; k < 4; ++k) {
            float x = xs[k];
            if (x > XTHRESH) {
                int lin = v * 4 + k;
                int n   = lin / ELEMS;
                int rem = lin - n * ELEMS;
                int ch  = rem / HW_;
                int pix = rem - ch * HW_;
                int a   = ch / C_;
                int c   = ch - a * C_;
                unsigned int flat = (unsigned int)((pix * A_ + a) * C_ + c);
                unsigned int u = orderable(__float_as_uint(x));
                unsigned int pos = atomicAdd(&cnt[n], 1u);
                if (pos < CAP)
                    cand[(size_t)n * CAP + pos] =
                        ((unsigned long long)u << 32) | (unsigned long long)(~flat);
            }
        }
    }
}

#define CHUNK 2048
__global__ __launch_bounds__(256)
void select_decode_kernel(const unsigned long long* __restrict__ cand,
                          const unsigned int* __restrict__ cnt,
                          const float* __restrict__ reg,
                          const float* __restrict__ anchors,
                          float4* __restrict__ oboxg,
                          float4* __restrict__ bboxg,
                          float* __restrict__ scg,
                          float* __restrict__ clsg) {
    const int img = blockIdx.y;
    const int M = (int)min(cnt[img], (unsigned int)CAP);
    if ((int)(blockIdx.x * blockDim.x) >= M) return;
    const int g = blockIdx.x * blockDim.x + threadIdx.x;
    __shared__ unsigned long long sk[CHUNK];
    unsigned long long mykey = (g < M) ? cand[(size_t)img * CAP + g] : 0ull;
    int rank = 0;
    for (int base = 0; base < M; base += CHUNK) {
        int cn = min(CHUNK, M - base);
        __syncthreads();
        for (int t = threadIdx.x; t < cn; t += blockDim.x)
            sk[t] = cand[(size_t)img * CAP + base + t];
        __syncthreads();
        if (g < M)
            for (int t = 0; t < cn; ++t) rank += (sk[t] > mykey);
    }
    if (g < M && rank < K_) {
        unsigned int u = (unsigned int)(mykey >> 32);
        unsigned int flat = ~((unsigned int)mykey);
        unsigned int b = (u & 0x80000000u) ? (u & 0x7fffffffu) : ~u;
        float x = __uint_as_float(b);
        float score = (float)(1.0 / (1.0 + exp(-(double)x)));
        int loc = (int)(flat / C_);
        int clsv = (int)(flat - (unsigned)loc * C_) + 1;
        int aa = loc % A_;
        int pix = loc / A_;
        int hh = pix / W_;
        int wwp = pix - hh * W_;
        float a0 = anchors[loc*4+0], a1 = anchors[loc*4+1];
        float a2 = anchors[loc*4+2], a3 = anchors[loc*4+3];
        int rbase = ((img * RCH + aa * 4) * H_ + hh) * W_ + wwp;
        float r0 = reg[rbase], r1 = reg[rbase + HW_];
        float r2 = reg[rbase + 2*HW_], r3 = reg[rbase + 3*HW_];
        float wA = a2 - a0 + 1.0f, hA = a3 - a1 + 1.0f;
        float cx = a0 + 0.5f * wA, cy = a1 + 0.5f * hA;
        float dx = r0 / 10.0f, dy = r1 / 10.0f;
        float dw = fminf(r2 / 5.0f, CLIPV), dh = fminf(r3 / 5.0f, CLIPV);
        float pcx = dx * wA + cx, pcy = dy * hA + cy;
        float pw = expf(dw) * wA, ph = expf(dh) * hA;
        float x1 = pcx - 0.5f * pw;
        float y1 = pcy - 0.5f * ph;
        float x2 = pcx + 0.5f * pw - 1.0f;
        float y2 = pcy + 0.5f * ph - 1.0f;
        x1 = fminf(fmaxf(x1, 0.0f), 1215.0f);
        y1 = fminf(fmaxf(y1, 0.0f), 799.0f);
        x2 = fminf(fmaxf(x2, 0.0f), 1215.0f);
        y2 = fminf(fmaxf(y2, 0.0f), 799.0f);
        bool ks = (x2 - x1 + 1.0f >= 0.0f) && (y2 - y1 + 1.0f >= 0.0f);
        if (!ks) score = -1.0f;
        float off = (float)clsv * 1218.0f;
        bboxg[img*K_ + rank] = make_float4(x1, y1, x2, y2);
        oboxg[img*K_ + rank] = make_float4(x1 + off, y1 + off, x2 + off, y2 + off);
        scg[img*K_ + rank] = score;
        clsg[img*K_ + rank] = (float)clsv;
    }
}

// grid (8, N_IMG) x 256 threads. tid&127 = row-in-block, tid>>7 = word-half.
__global__ __launch_bounds__(256)
void mask_kernel(const float4* __restrict__ oboxg,
                 unsigned long long* __restrict__ maskT,
                 unsigned long long* __restrict__ tdiag) {
    const int img = blockIdx.y;
    __shared__ float4 ob[K_];
    __shared__ float areaL[K_];
    for (int t = threadIdx.x; t < K_; t += 256) {
        float4 v = oboxg[img*K_ + t];
        ob[t] = v;
        areaL[t] = (v.z - v.x + 1.0f) * (v.w - v.y + 1.0f);
    }
    __syncthreads();
    const int rloc = threadIdx.x & 127;
    const int h = threadIdx.x >> 7;
    const int r = blockIdx.x * 128 + rloc;
    const bool valid = r < K_;
    const int wr = r >> 6;
    float4 a = ob[valid ? r : 0];
    float aarea = areaL[valid ? r : 0];
    unsigned long long dj = 0ull;
    if (valid) {
        const int base = 64 * (16 * wr - ((wr * (wr - 1)) >> 1)) + (r & 63) * (16 - wr);
        unsigned long long* row = maskT + (size_t)img * MWORDS + base;
        const int wlo = max(wr, h * 8);
        const int whi = min(15, h * 8 + 7);
        for (int wd = wlo; wd <= whi; ++wd) {
            unsigned long long m = 0ull;
            const int jbase = wd << 6;
            const int jend = min(64, K_ - jbase);
            for (int jj = 0; jj < jend; ++jj) {
                float4 bb = ob[jbase + jj];          // wave-uniform addr -> LDS broadcast
                float ix1 = fmaxf(a.x, bb.x);
                float iy1 = fmaxf(a.y, bb.y);
                float ix2 = fminf(a.z, bb.z);
                float iy2 = fminf(a.w, bb.w);
                float iw = fmaxf(ix2 - ix1 + 1.0f, 0.0f);
                float ih = fmaxf(iy2 - iy1 + 1.0f, 0.0f);
                float inter = iw * ih;
                float iou = inter / (aarea + areaL[jbase + jj] - inter);
                if (iou > NMS_T) m |= (1ull << jj);
            }
            if (wd == wr) { m &= (~1ull) << (r & 63); dj = m; }
            row[wd - wr] = m;
        }
    }
    // ballot-transpose the diagonal 64x64 tile; only the half that owns wd==wr writes
    const int l = threadIdx.x & 63;
    const int wave = threadIdx.x >> 6;         // 0..3
    const int win = blockIdx.x * 2 + (wave & 1);
    if (h == (win >> 3)) {
        unsigned long long src = 0ull;
        for (int t = 0; t < 64; ++t) {
            unsigned long long col = __ballot(((dj >> t) & 1ull) != 0ull);
            if (l == t) src = col;
        }
        tdiag[(size_t)img * 1024 + win * 64 + l] = src;
    }
}

__global__ __launch_bounds__(1024)
void sweep_out_kernel(const float4* __restrict__ bboxg,
                      const float* __restrict__ scg,
                      const float* __restrict__ clsg,
                      const unsigned long long* __restrict__ tdiag,
                      const unsigned long long* __restrict__ maskT,
                      float* __restrict__ out) {
    const int img = blockIdx.x;
    __shared__ float scL[1024];
    __shared__ unsigned long long keepw[16];
    __shared__ int totkeep;
    const int i = threadIdx.x;
    scL[i] = (i < K_) ? scg[img*K_ + i] : -1.0f;
    __syncthreads();

    if (i < 64) {
        const int l = i;
        const unsigned long long* td = tdiag + (size_t)img * 1024;
        const unsigned long long* mT = maskT + (size_t)img * MWORDS;
        unsigned long long srcv[16];
        #pragma unroll
        for (int w = 0; w < 16; ++w) srcv[w] = td[w * 64 + l];
        unsigned long long R = 0ull;
        const int sb = (l >> 4) << 4;
        const int myw = l & 15;
        #pragma unroll
        for (int w = 0; w < 16; ++w) {
            unsigned long long ww = __shfl(R, w) | __shfl(R, w + 16) |
                                    __shfl(R, w + 32) | __shfl(R, w + 48);
            bool dead = (scL[(w << 6) + l] < 0.0f) || (((ww >> l) & 1ull) != 0ull);
            unsigned long long supp = dead ? 1ull : 0ull;
            const unsigned long long src = srcv[w];
            // register-only sequential greedy scan over the 64 rows of this window
            for (int b = 0; b < 64; ++b) {
                unsigned long long av = __ballot(supp == 0ull);
                supp |= ((av >> b) & (src >> b)) & 1ull;
            }
            unsigned long long avf = __ballot(supp == 0ull);
            if (l == 0) keepw[w] = avf;
            // accumulate cross-window suppression words of alive rows
            if (myw >= w) {
                const int rlen = 16 - w;
                const unsigned long long* mrow =
                    mT + 64 * (16 * w - ((w * (w - 1)) >> 1)) + (myw - w);
                for (int t = 0; t < 16; ++t) {
                    const int b = sb + t;
                    if ((avf >> b) & 1ull) R |= mrow[(size_t)b * rlen];
                }
            }
        }
    }
    __syncthreads();
    if (i == 0) {
        int t = 0;
        for (int w = 0; w < 16; ++w) t += __popcll(keepw[w]);
        totkeep = t;
    }
    __syncthreads();

    if (i < K_) {
        int wv = i >> 6, bt = i & 63;
        bool kept = (keepw[wv] >> bt) & 1ull;
        int pre = 0;
        for (int t = 0; t < wv; ++t) pre += __popcll(keepw[t]);
        if (bt) pre += __popcll(keepw[wv] & ((~0ull) >> (64 - bt)));
        int slot = -1;
        float outsc = -1.0f;
        if (kept) {
            if (pre < OUT_TOP) slot = pre;
            outsc = scL[i];
        } else {
            int s = totkeep + (i - pre);
            if (s < OUT_TOP) slot = s;
        }
        if (slot >= 0) {
            float4 bb = bboxg[img*K_ + i];
            float* ob = out + (size_t)img * OUT_TOP * 4;
            ob[slot*4+0] = bb.x;
            ob[slot*4+1] = bb.y;
            ob[slot*4+2] = bb.z;
            ob[slot*4+3] = bb.w;
            out[N_IMG*OUT_TOP*4 + img*OUT_TOP + slot] = outsc;
            out[N_IMG*OUT_TOP*5 + img*OUT_TOP + slot] = clsg[img*K_ + i];
        }
    }
}

extern "C" void kernel_launch(void* const* d_in, const int* in_sizes, int n_in,
                              void* d_out, int out_size, void* d_ws, size_t ws_size,
                              hipStream_t stream) {
    const float* box_cls = (const float*)d_in[0];
    const float* box_reg = (const float*)d_in[1];
    const float* anchors = (const float*)d_in[2];
    float* out = (float*)d_out;

    char* ws = (char*)d_ws;
    unsigned int* cnt          = (unsigned int*)ws;
    float4* oboxg              = (float4*)(ws + WS_OBOX);
    float4* bboxg              = (float4*)(ws + WS_BBOX);
    float* scg                 = (float*)(ws + WS_SC);
    float* clsg                = (float*)(ws + WS_CLS);
    unsigned long long* tdiag  = (unsigned long long*)(ws + WS_TD);
    unsigned long long* maskT  = (unsigned long long*)(ws + WS_MASK);
    unsigned long long* cand   = (unsigned long long*)(ws + WS_CAND);

    hipLaunchKernelGGL(init_kernel, dim3(N_IMG), dim3(1024), 0, stream,
                       cnt, oboxg, bboxg, scg, clsg);
    hipLaunchKernelGGL(collect_kernel, dim3(2048), dim3(256), 0, stream,
                       box_cls, cand, cnt);
    hipLaunchKernelGGL(select_decode_kernel, dim3(CAP / 256, N_IMG), dim3(256), 0, stream,
                       cand, cnt, box_reg, anchors, oboxg, bboxg, scg, clsg);
    hipLaunchKernelGGL(mask_kernel, dim3(8, N_IMG), dim3(256), 0, stream,
                       oboxg, maskT, tdiag);
    hipLaunchKernelGGL(sweep_out_kernel, dim3(N_IMG), dim3(1024), 0, stream,
                       bboxg, scg, clsg, tdiag, maskT, out);
}

// Round 5
// 350.201 us; speedup vs baseline: 2.5766x; 1.0849x over previous
//
#include <hip/hip_runtime.h>
#include <math.h>

#define N_IMG 2
#define A_ 9
#define C_ 80
#define H_ 100
#define W_ 152
#define HW_ (H_*W_)            // 15200
#define ACH 720                // A*C channels of box_cls
#define RCH 36                 // A*4 channels of box_regression
#define ELEMS (ACH*HW_)        // 10,944,000 per image
#define TOTAL (N_IMG*ELEMS)    // 21,888,000
#define K_ 1000
#define OUT_TOP 100
#define XTHRESH (-0.6f)
#define CLIPV 4.135166556742356f
#define NMS_T 0.5f
#define NSEG 16
#define SEGCAP 512
#define MAXM (NSEG*SEGCAP)     // 8192
#define TILES 136              // triangular 64x64 tiles for 16x16 windows

// ws layout (bytes):
//   [0, 4096)        u32 cnt[2][NSEG] padded: index (img*NSEG+seg)*32
//   [4096, 36096)    float4 obox[2][1000]
//   [36096, 68096)   float4 bbox[2][1000]
//   [68096, 76096)   float  sc[2][1000]
//   [76096, 84096)   float  cls[2][1000]
//   [84096, 215168)  u64    cand[2][NSEG][SEGCAP]
#define WS_OBOX 4096
#define WS_BBOX 36096
#define WS_SC   68096
#define WS_CLS  76096
#define WS_CAND 84096

__device__ __forceinline__ unsigned int orderable(unsigned int b) {
    return (b & 0x80000000u) ? ~b : (b | 0x80000000u);
}
__device__ __forceinline__ int tri_start(int b) {   // tiles before band b
    return b * 16 - ((b * (b - 1)) >> 1);
}

__global__ void init_kernel(unsigned int* __restrict__ cnt,
                            float4* __restrict__ oboxg,
                            float4* __restrict__ bboxg,
                            float* __restrict__ scg,
                            float* __restrict__ clsg) {
    const int img = blockIdx.x;
    const int i = threadIdx.x;
    if (img == 0) cnt[i] = 0u;   // 1024 threads cover the 4KB padded region
    if (i < K_) {
        oboxg[img*K_ + i] = make_float4(0.f, 0.f, 0.f, 0.f);
        bboxg[img*K_ + i] = make_float4(0.f, 0.f, 0.f, 0.f);
        scg[img*K_ + i] = -1.0f;
        clsg[img*K_ + i] = 0.0f;
    }
}

__global__ void collect_kernel(const float* __restrict__ cls,
                               unsigned long long* __restrict__ cand,
                               unsigned int* __restrict__ cnt) {
    const int nvec = TOTAL / 4;
    const int seg = blockIdx.x & (NSEG - 1);
    for (int v = blockIdx.x * blockDim.x + threadIdx.x; v < nvec;
         v += gridDim.x * blockDim.x) {
        float4 f = ((const float4*)cls)[v];
        float xs[4] = {f.x, f.y, f.z, f.w};
        #pragma unroll
        for (int k = 0; k < 4; ++k) {
            float x = xs[k];
            if (x > XTHRESH) {
                int lin = v * 4 + k;
                int n   = lin / ELEMS;
                int rem = lin - n * ELEMS;
                int ch  = rem / HW_;
                int pix = rem - ch * HW_;
                int a   = ch / C_;
                int c   = ch - a * C_;
                unsigned int flat = (unsigned int)((pix * A_ + a) * C_ + c);
                unsigned int u = orderable(__float_as_uint(x));
                unsigned int pos = atomicAdd(&cnt[(n * NSEG + seg) * 32], 1u);
                if (pos < SEGCAP)
                    cand[((size_t)n * NSEG + seg) * SEGCAP + pos] =
                        ((unsigned long long)u << 32) | (unsigned long long)(~flat);
            }
        }
    }
}

__global__ __launch_bounds__(256)
void select_decode_kernel(const unsigned long long* __restrict__ cand,
                          const unsigned int* __restrict__ cnt,
                          const float* __restrict__ reg,
                          const float* __restrict__ anchors,
                          float4* __restrict__ oboxg,
                          float4* __restrict__ bboxg,
                          float* __restrict__ scg,
                          float* __restrict__ clsg) {
    const int img = blockIdx.y;
    int cbase[NSEG + 1];
    int acc = 0;
    #pragma unroll
    for (int s = 0; s < NSEG; ++s) {
        cbase[s] = acc;
        acc += (int)min(cnt[(img * NSEG + s) * 32], (unsigned int)SEGCAP);
    }
    cbase[NSEG] = acc;
    const int M = acc;
    if ((int)(blockIdx.x * blockDim.x) >= M) return;

    __shared__ unsigned long long sk[MAXM];
    #pragma unroll
    for (int s = 0; s < NSEG; ++s) {
        const int cn = cbase[s + 1] - cbase[s];
        const unsigned long long* src = cand + ((size_t)img * NSEG + s) * SEGCAP;
        for (int t = threadIdx.x; t < cn; t += 256)
            sk[cbase[s] + t] = src[t];
    }
    __syncthreads();

    const int g = blockIdx.x * blockDim.x + threadIdx.x;
    if (g >= M) return;
    const unsigned long long mykey = sk[g];
    int rank = 0;
    for (int t = 0; t < M; ++t) rank += (sk[t] > mykey);
    if (rank >= K_) return;

    unsigned int u = (unsigned int)(mykey >> 32);
    unsigned int flat = ~((unsigned int)mykey);
    unsigned int b = (u & 0x80000000u) ? (u & 0x7fffffffu) : ~u;
    float x = __uint_as_float(b);
    float score = (float)(1.0 / (1.0 + exp(-(double)x)));
    int loc = (int)(flat / C_);
    int clsv = (int)(flat - (unsigned)loc * C_) + 1;
    int aa = loc % A_;
    int pix = loc / A_;
    int hh = pix / W_;
    int wwp = pix - hh * W_;
    float a0 = anchors[loc*4+0], a1 = anchors[loc*4+1];
    float a2 = anchors[loc*4+2], a3 = anchors[loc*4+3];
    int rbase = ((img * RCH + aa * 4) * H_ + hh) * W_ + wwp;
    float r0 = reg[rbase], r1 = reg[rbase + HW_];
    float r2 = reg[rbase + 2*HW_], r3 = reg[rbase + 3*HW_];
    float wA = a2 - a0 + 1.0f, hA = a3 - a1 + 1.0f;
    float cx = a0 + 0.5f * wA, cy = a1 + 0.5f * hA;
    float dx = r0 / 10.0f, dy = r1 / 10.0f;
    float dw = fminf(r2 / 5.0f, CLIPV), dh = fminf(r3 / 5.0f, CLIPV);
    float pcx = dx * wA + cx, pcy = dy * hA + cy;
    float pw = expf(dw) * wA, ph = expf(dh) * hA;
    float x1 = pcx - 0.5f * pw;
    float y1 = pcy - 0.5f * ph;
    float x2 = pcx + 0.5f * pw - 1.0f;
    float y2 = pcy + 0.5f * ph - 1.0f;
    x1 = fminf(fmaxf(x1, 0.0f), 1215.0f);
    y1 = fminf(fmaxf(y1, 0.0f), 799.0f);
    x2 = fminf(fmaxf(x2, 0.0f), 1215.0f);
    y2 = fminf(fmaxf(y2, 0.0f), 799.0f);
    bool ks = (x2 - x1 + 1.0f >= 0.0f) && (y2 - y1 + 1.0f >= 0.0f);
    if (!ks) score = -1.0f;
    float off = (float)clsv * 1218.0f;
    bboxg[img*K_ + rank] = make_float4(x1, y1, x2, y2);
    oboxg[img*K_ + rank] = make_float4(x1 + off, y1 + off, x2 + off, y2 + off);
    scg[img*K_ + rank] = score;
    clsg[img*K_ + rank] = (float)clsv;
}

// One block per image. Mask lives entirely in LDS.
__global__ __launch_bounds__(1024)
void nms_out_kernel(const float4* __restrict__ oboxg,
                    const float4* __restrict__ bboxg,
                    const float* __restrict__ scg,
                    const float* __restrict__ clsg,
                    float* __restrict__ out) {
    const int img = blockIdx.x;
    __shared__ float4 ob[K_];
    __shared__ float areaL[K_];
    __shared__ float scL[1024];
    __shared__ unsigned long long maskL[TILES * 64];   // 69,632 B, tile-column-major
    __shared__ unsigned long long tdiag[1024];
    __shared__ unsigned long long keepw[16];
    __shared__ int totkeep;

    const int tid = threadIdx.x;
    scL[tid] = (tid < K_) ? scg[img*K_ + tid] : -1.0f;
    for (int t = tid; t < K_; t += 1024) {
        float4 v = oboxg[img*K_ + t];
        ob[t] = v;
        areaL[t] = (v.z - v.x + 1.0f) * (v.w - v.y + 1.0f);
    }
    __syncthreads();

    const int wave = tid >> 6;
    const int lane = tid & 63;
    for (int ti = wave; ti < TILES; ti += 16) {       // ti wave-uniform
        int bnd = 0;
        while (tri_start(bnd + 1) <= ti) ++bnd;
        const int wd = bnd + (ti - tri_start(bnd));
        const int r = bnd * 64 + lane;
        const bool rv = r < K_;
        float4 a = ob[rv ? r : 0];
        float aar = areaL[rv ? r : 0];
        const int jbase = wd << 6;
        const int jend = min(64, K_ - jbase);
        unsigned long long m = 0ull;
        for (int jj = 0; jj < jend; ++jj) {
            float4 bb = ob[jbase + jj];               // wave-uniform -> broadcast
            float ix1 = fmaxf(a.x, bb.x);
            float iy1 = fmaxf(a.y, bb.y);
            float ix2 = fminf(a.z, bb.z);
            float iy2 = fminf(a.w, bb.w);
            float iw = fmaxf(ix2 - ix1 + 1.0f, 0.0f);
            float ih = fmaxf(iy2 - iy1 + 1.0f, 0.0f);
            float inter = iw * ih;
            float iou = inter / (aar + areaL[jbase + jj] - inter);
            if (iou > NMS_T) m |= (1ull << jj);
        }
        if (!rv) m = 0ull;
        if (wd == bnd) m &= (~1ull) << (r & 63);      // keep only j > r
        maskL[(tri_start(bnd) + (wd - bnd)) * 64 + lane] = m;
        if (wd == bnd) {                              // ballot-transpose diagonal
            unsigned long long src = 0ull;
            for (int t = 0; t < 64; ++t) {
                unsigned long long col = __ballot(((m >> t) & 1ull) != 0ull);
                if (lane == t) src = col;
            }
            tdiag[bnd * 64 + lane] = src;
        }
    }
    __syncthreads();

    if (tid < 64) {
        const int l = tid;
        unsigned long long srcv[16];
        #pragma unroll
        for (int w = 0; w < 16; ++w) srcv[w] = tdiag[w * 64 + l];
        unsigned long long R = 0ull;
        const int sb = (l >> 4) << 4;
        const int myw = l & 15;
        #pragma unroll
        for (int w = 0; w < 16; ++w) {
            unsigned long long ww = __shfl(R, w) | __shfl(R, w + 16) |
                                    __shfl(R, w + 32) | __shfl(R, w + 48);
            bool dead = (scL[(w << 6) + l] < 0.0f) || (((ww >> l) & 1ull) != 0ull);
            unsigned long long supp = dead ? 1ull : 0ull;
            const unsigned long long src = srcv[w];
            for (int b2 = 0; b2 < 64; ++b2) {
                unsigned long long av = __ballot(supp == 0ull);
                supp |= ((av >> b2) & (src >> b2)) & 1ull;
            }
            unsigned long long avf = __ballot(supp == 0ull);
            if (l == 0) keepw[w] = avf;
            if (myw >= w) {
                const unsigned long long* base =
                    &maskL[(tri_start(w) + (myw - w)) * 64];
                for (int t = 0; t < 16; ++t) {
                    const int b2 = sb + t;
                    if ((avf >> b2) & 1ull) R |= base[b2];
                }
            }
        }
    }
    __syncthreads();
    if (tid == 0) {
        int t = 0;
        for (int w = 0; w < 16; ++w) t += __popcll(keepw[w]);
        totkeep = t;
    }
    __syncthreads();

    if (tid < K_) {
        const int i = tid;
        int wv = i >> 6, bt = i & 63;
        bool kept = (keepw[wv] >> bt) & 1ull;
        int pre = 0;
        for (int t = 0; t < wv; ++t) pre += __popcll(keepw[t]);
        if (bt) pre += __popcll(keepw[wv] & ((~0ull) >> (64 - bt)));
        int slot = -1;
        float outsc = -1.0f;
        if (kept) {
            if (pre < OUT_TOP) slot = pre;
            outsc = scL[i];
        } else {
            int s = totkeep + (i - pre);
            if (s < OUT_TOP) slot = s;
        }
        if (slot >= 0) {
            float4 bb = bboxg[img*K_ + i];
            float* obp = out + (size_t)img * OUT_TOP * 4;
            obp[slot*4+0] = bb.x;
            obp[slot*4+1] = bb.y;
            obp[slot*4+2] = bb.z;
            obp[slot*4+3] = bb.w;
            out[N_IMG*OUT_TOP*4 + img*OUT_TOP + slot] = outsc;
            out[N_IMG*OUT_TOP*5 + img*OUT_TOP + slot] = clsg[img*K_ + i];
        }
    }
}

extern "C" void kernel_launch(void* const* d_in, const int* in_sizes, int n_in,
                              void* d_out, int out_size, void* d_ws, size_t ws_size,
                              hipStream_t stream) {
    const float* box_cls = (const float*)d_in[0];
    const float* box_reg = (const float*)d_in[1];
    const float* anchors = (const float*)d_in[2];
    float* out = (float*)d_out;

    char* ws = (char*)d_ws;
    unsigned int* cnt        = (unsigned int*)ws;
    float4* oboxg            = (float4*)(ws + WS_OBOX);
    float4* bboxg            = (float4*)(ws + WS_BBOX);
    float* scg               = (float*)(ws + WS_SC);
    float* clsg              = (float*)(ws + WS_CLS);
    unsigned long long* cand = (unsigned long long*)(ws + WS_CAND);

    hipLaunchKernelGGL(init_kernel, dim3(N_IMG), dim3(1024), 0, stream,
                       cnt, oboxg, bboxg, scg, clsg);
    hipLaunchKernelGGL(collect_kernel, dim3(2048), dim3(256), 0, stream,
                       box_cls, cand, cnt);
    hipLaunchKernelGGL(select_decode_kernel, dim3(MAXM / 256, N_IMG), dim3(256), 0, stream,
                       cand, cnt, box_reg, anchors, oboxg, bboxg, scg, clsg);
    hipLaunchKernelGGL(nms_out_kernel, dim3(N_IMG), dim3(1024), 0, stream,
                       oboxg, bboxg, scg, clsg, out);
}

// Round 6
// 262.309 us; speedup vs baseline: 3.4399x; 1.3351x over previous
//
#include <hip/hip_runtime.h>
#include <math.h>

#define N_IMG 2
#define A_ 9
#define C_ 80
#define H_ 100
#define W_ 152
#define HW_ (H_*W_)            // 15200
#define ACH 720                // A*C channels of box_cls
#define RCH 36                 // A*4 channels of box_regression
#define ELEMS (ACH*HW_)        // 10,944,000 per image
#define TOTAL (N_IMG*ELEMS)    // 21,888,000
#define K_ 1000
#define OUT_TOP 100
#define XTHRESH (-0.6f)
#define CLIPV 4.135166556742356f
#define NSEG 16
#define SEGCAP 512
#define MAXM (NSEG*SEGCAP)     // 8192
#define TILES 136              // triangular 64x64 tiles for 16x16 windows
#define MWORDS (TILES*64)      // 8704 u64 per image

// ws layout (bytes):
//   [0, 4096)          u32 cnt[2][NSEG] padded: index (img*NSEG+seg)*32
//   [4096, 36096)      float4 obox[2][1000]
//   [36096, 68096)     float4 bbox[2][1000]
//   [68096, 76096)     float  sc[2][1000]
//   [76096, 84096)     float  cls[2][1000]
//   [84096, 215168)    u64    cand[2][NSEG][SEGCAP]
//   [215168, 231552)   u64    tdiag[2][1024]
//   [231552, 370816)   u64    maskT[2][MWORDS]  (tile-major: tile*64 + row)
#define WS_OBOX 4096
#define WS_BBOX 36096
#define WS_SC   68096
#define WS_CLS  76096
#define WS_CAND 84096
#define WS_TD   215168
#define WS_MASK 231552

__device__ __forceinline__ unsigned int orderable(unsigned int b) {
    return (b & 0x80000000u) ? ~b : (b | 0x80000000u);
}
__device__ __forceinline__ int tri_start(int b) {   // tiles before band b
    return b * 16 - ((b * (b - 1)) >> 1);
}

__global__ void init_kernel(unsigned int* __restrict__ cnt,
                            float4* __restrict__ oboxg,
                            float4* __restrict__ bboxg,
                            float* __restrict__ scg,
                            float* __restrict__ clsg) {
    const int img = blockIdx.x;
    const int i = threadIdx.x;
    if (img == 0) cnt[i] = 0u;   // 1024 threads cover the 4KB padded region
    if (i < K_) {
        oboxg[img*K_ + i] = make_float4(0.f, 0.f, 0.f, 0.f);
        bboxg[img*K_ + i] = make_float4(0.f, 0.f, 0.f, 0.f);
        scg[img*K_ + i] = -1.0f;
        clsg[img*K_ + i] = 0.0f;
    }
}

__global__ void collect_kernel(const float* __restrict__ cls,
                               unsigned long long* __restrict__ cand,
                               unsigned int* __restrict__ cnt) {
    const int nvec = TOTAL / 4;
    const int seg = blockIdx.x & (NSEG - 1);
    for (int v = blockIdx.x * blockDim.x + threadIdx.x; v < nvec;
         v += gridDim.x * blockDim.x) {
        float4 f = ((const float4*)cls)[v];
        float xs[4] = {f.x, f.y, f.z, f.w};
        #pragma unroll
        for (int k = 0; k < 4; ++k) {
            float x = xs[k];
            if (x > XTHRESH) {
                int lin = v * 4 + k;
                int n   = lin / ELEMS;
                int rem = lin - n * ELEMS;
                int ch  = rem / HW_;
                int pix = rem - ch * HW_;
                int a   = ch / C_;
                int c   = ch - a * C_;
                unsigned int flat = (unsigned int)((pix * A_ + a) * C_ + c);
                unsigned int u = orderable(__float_as_uint(x));
                unsigned int pos = atomicAdd(&cnt[(n * NSEG + seg) * 32], 1u);
                if (pos < SEGCAP)
                    cand[((size_t)n * NSEG + seg) * SEGCAP + pos] =
                        ((unsigned long long)u << 32) | (unsigned long long)(~flat);
            }
        }
    }
}

__global__ __launch_bounds__(256)
void select_decode_kernel(const unsigned long long* __restrict__ cand,
                          const unsigned int* __restrict__ cnt,
                          const float* __restrict__ reg,
                          const float* __restrict__ anchors,
                          float4* __restrict__ oboxg,
                          float4* __restrict__ bboxg,
                          float* __restrict__ scg,
                          float* __restrict__ clsg) {
    const int img = blockIdx.y;
    int cbase[NSEG + 1];
    int acc = 0;
    #pragma unroll
    for (int s = 0; s < NSEG; ++s) {
        cbase[s] = acc;
        acc += (int)min(cnt[(img * NSEG + s) * 32], (unsigned int)SEGCAP);
    }
    cbase[NSEG] = acc;
    const int M = acc;
    if ((int)(blockIdx.x * blockDim.x) >= M) return;

    __shared__ unsigned long long sk[MAXM];
    #pragma unroll
    for (int s = 0; s < NSEG; ++s) {
        const int cn = cbase[s + 1] - cbase[s];
        const unsigned long long* src = cand + ((size_t)img * NSEG + s) * SEGCAP;
        for (int t = threadIdx.x; t < cn; t += 256)
            sk[cbase[s] + t] = src[t];
    }
    __syncthreads();

    const int g = blockIdx.x * blockDim.x + threadIdx.x;
    if (g >= M) return;
    const unsigned long long mykey = sk[g];
    int rank = 0;
    for (int t = 0; t < M; ++t) rank += (sk[t] > mykey);
    if (rank >= K_) return;

    unsigned int u = (unsigned int)(mykey >> 32);
    unsigned int flat = ~((unsigned int)mykey);
    unsigned int b = (u & 0x80000000u) ? (u & 0x7fffffffu) : ~u;
    float x = __uint_as_float(b);
    float score = (float)(1.0 / (1.0 + exp(-(double)x)));
    int loc = (int)(flat / C_);
    int clsv = (int)(flat - (unsigned)loc * C_) + 1;
    int aa = loc % A_;
    int pix = loc / A_;
    int hh = pix / W_;
    int wwp = pix - hh * W_;
    float a0 = anchors[loc*4+0], a1 = anchors[loc*4+1];
    float a2 = anchors[loc*4+2], a3 = anchors[loc*4+3];
    int rbase = ((img * RCH + aa * 4) * H_ + hh) * W_ + wwp;
    float r0 = reg[rbase], r1 = reg[rbase + HW_];
    float r2 = reg[rbase + 2*HW_], r3 = reg[rbase + 3*HW_];
    float wA = a2 - a0 + 1.0f, hA = a3 - a1 + 1.0f;
    float cx = a0 + 0.5f * wA, cy = a1 + 0.5f * hA;
    float dx = r0 / 10.0f, dy = r1 / 10.0f;
    float dw = fminf(r2 / 5.0f, CLIPV), dh = fminf(r3 / 5.0f, CLIPV);
    float pcx = dx * wA + cx, pcy = dy * hA + cy;
    float pw = expf(dw) * wA, ph = expf(dh) * hA;
    float x1 = pcx - 0.5f * pw;
    float y1 = pcy - 0.5f * ph;
    float x2 = pcx + 0.5f * pw - 1.0f;
    float y2 = pcy + 0.5f * ph - 1.0f;
    x1 = fminf(fmaxf(x1, 0.0f), 1215.0f);
    y1 = fminf(fmaxf(y1, 0.0f), 799.0f);
    x2 = fminf(fmaxf(x2, 0.0f), 1215.0f);
    y2 = fminf(fmaxf(y2, 0.0f), 799.0f);
    bool ks = (x2 - x1 + 1.0f >= 0.0f) && (y2 - y1 + 1.0f >= 0.0f);
    if (!ks) score = -1.0f;
    float off = (float)clsv * 1218.0f;
    bboxg[img*K_ + rank] = make_float4(x1, y1, x2, y2);
    oboxg[img*K_ + rank] = make_float4(x1 + off, y1 + off, x2 + off, y2 + off);
    scg[img*K_ + rank] = score;
    clsg[img*K_ + rank] = (float)clsv;
}

// grid (17, N_IMG) x 256: 8 tiles per block, 2 per wave. Division-free IoU test.
__global__ __launch_bounds__(256)
void mask_kernel(const float4* __restrict__ oboxg,
                 unsigned long long* __restrict__ maskT,
                 unsigned long long* __restrict__ tdiag) {
    const int img = blockIdx.y;
    __shared__ float4 ob[K_];
    __shared__ float areaL[K_];
    for (int t = threadIdx.x; t < K_; t += 256) {
        float4 v = oboxg[img*K_ + t];
        ob[t] = v;
        areaL[t] = (v.z - v.x + 1.0f) * (v.w - v.y + 1.0f);
    }
    __syncthreads();

    const int wave = threadIdx.x >> 6;
    const int lane = threadIdx.x & 63;
    #pragma unroll
    for (int s = 0; s < 2; ++s) {
        const int ti = blockIdx.x * 8 + wave * 2 + s;   // wave-uniform, < 136
        int bnd = 0;
        while (tri_start(bnd + 1) <= ti) ++bnd;
        const int wd = bnd + (ti - tri_start(bnd));
        const int r = bnd * 64 + lane;
        const bool rv = r < K_;
        float4 a = ob[rv ? r : 0];
        float aar = areaL[rv ? r : 0];
        const int jbase = wd << 6;
        const int jend = min(64, K_ - jbase);
        unsigned long long m = 0ull;
        for (int jj = 0; jj < jend; ++jj) {
            float4 bb = ob[jbase + jj];               // wave-uniform -> broadcast
            float ix1 = fmaxf(a.x, bb.x);
            float iy1 = fmaxf(a.y, bb.y);
            float ix2 = fminf(a.z, bb.z);
            float iy2 = fminf(a.w, bb.w);
            float iw = fmaxf(ix2 - ix1 + 1.0f, 0.0f);
            float ih = fmaxf(iy2 - iy1 + 1.0f, 0.0f);
            float inter = iw * ih;
            // iou > 0.5  <=>  3*inter > area_i + area_j   (union = sum - inter > 0)
            if (3.0f * inter > aar + areaL[jbase + jj]) m |= (1ull << jj);
        }
        if (!rv) m = 0ull;
        if (wd == bnd) m &= (~1ull) << (r & 63);      // keep only j > r
        maskT[(size_t)img * MWORDS + ti * 64 + lane] = m;
        if (wd == bnd) {                              // ballot-transpose diagonal
            unsigned long long src = 0ull;
            for (int t = 0; t < 64; ++t) {
                unsigned long long col = __ballot(((m >> t) & 1ull) != 0ull);
                if (lane == t) src = col;
            }
            tdiag[(size_t)img * 1024 + bnd * 64 + lane] = src;
        }
    }
}

__global__ __launch_bounds__(1024)
void sweep_out_kernel(const float4* __restrict__ bboxg,
                      const float* __restrict__ scg,
                      const float* __restrict__ clsg,
                      const unsigned long long* __restrict__ tdiag,
                      const unsigned long long* __restrict__ maskT,
                      float* __restrict__ out) {
    const int img = blockIdx.x;
    __shared__ float scL[1024];
    __shared__ unsigned long long keepw[16];
    __shared__ int totkeep;
    const int tid = threadIdx.x;
    scL[tid] = (tid < K_) ? scg[img*K_ + tid] : -1.0f;
    __syncthreads();

    if (tid < 64) {
        const int l = tid;
        const unsigned long long* td = tdiag + (size_t)img * 1024;
        const unsigned long long* mT = maskT + (size_t)img * MWORDS;
        unsigned long long srcv[16];
        #pragma unroll
        for (int w = 0; w < 16; ++w) srcv[w] = td[w * 64 + l];
        unsigned long long R = 0ull;
        const int sb = (l >> 4) << 4;
        const int myw = l & 15;
        #pragma unroll
        for (int w = 0; w < 16; ++w) {
            unsigned long long ww = __shfl(R, w) | __shfl(R, w + 16) |
                                    __shfl(R, w + 32) | __shfl(R, w + 48);
            bool dead = (scL[(w << 6) + l] < 0.0f) || (((ww >> l) & 1ull) != 0ull);
            unsigned long long supp = dead ? 1ull : 0ull;
            const unsigned long long src = srcv[w];
            for (int b2 = 0; b2 < 64; ++b2) {
                unsigned long long av = __ballot(supp == 0ull);
                supp |= ((av >> b2) & (src >> b2)) & 1ull;
            }
            unsigned long long avf = __ballot(supp == 0ull);
            if (l == 0) keepw[w] = avf;
            if (myw >= w) {
                const unsigned long long* base =
                    mT + (size_t)(tri_start(w) + (myw - w)) * 64;
                for (int t = 0; t < 16; ++t) {
                    const int b2 = sb + t;
                    if ((avf >> b2) & 1ull) R |= base[b2];
                }
            }
        }
    }
    __syncthreads();
    if (tid == 0) {
        int t = 0;
        for (int w = 0; w < 16; ++w) t += __popcll(keepw[w]);
        totkeep = t;
    }
    __syncthreads();

    if (tid < K_) {
        const int i = tid;
        int wv = i >> 6, bt = i & 63;
        bool kept = (keepw[wv] >> bt) & 1ull;
        int pre = 0;
        for (int t = 0; t < wv; ++t) pre += __popcll(keepw[t]);
        if (bt) pre += __popcll(keepw[wv] & ((~0ull) >> (64 - bt)));
        int slot = -1;
        float outsc = -1.0f;
        if (kept) {
            if (pre < OUT_TOP) slot = pre;
            outsc = scL[i];
        } else {
            int s = totkeep + (i - pre);
            if (s < OUT_TOP) slot = s;
        }
        if (slot >= 0) {
            float4 bb = bboxg[img*K_ + i];
            float* obp = out + (size_t)img * OUT_TOP * 4;
            obp[slot*4+0] = bb.x;
            obp[slot*4+1] = bb.y;
            obp[slot*4+2] = bb.z;
            obp[slot*4+3] = bb.w;
            out[N_IMG*OUT_TOP*4 + img*OUT_TOP + slot] = outsc;
            out[N_IMG*OUT_TOP*5 + img*OUT_TOP + slot] = clsg[img*K_ + i];
        }
    }
}

extern "C" void kernel_launch(void* const* d_in, const int* in_sizes, int n_in,
                              void* d_out, int out_size, void* d_ws, size_t ws_size,
                              hipStream_t stream) {
    const float* box_cls = (const float*)d_in[0];
    const float* box_reg = (const float*)d_in[1];
    const float* anchors = (const float*)d_in[2];
    float* out = (float*)d_out;

    char* ws = (char*)d_ws;
    unsigned int* cnt         = (unsigned int*)ws;
    float4* oboxg             = (float4*)(ws + WS_OBOX);
    float4* bboxg             = (float4*)(ws + WS_BBOX);
    float* scg                = (float*)(ws + WS_SC);
    float* clsg               = (float*)(ws + WS_CLS);
    unsigned long long* cand  = (unsigned long long*)(ws + WS_CAND);
    unsigned long long* tdiag = (unsigned long long*)(ws + WS_TD);
    unsigned long long* maskT = (unsigned long long*)(ws + WS_MASK);

    hipLaunchKernelGGL(init_kernel, dim3(N_IMG), dim3(1024), 0, stream,
                       cnt, oboxg, bboxg, scg, clsg);
    hipLaunchKernelGGL(collect_kernel, dim3(2048), dim3(256), 0, stream,
                       box_cls, cand, cnt);
    hipLaunchKernelGGL(select_decode_kernel, dim3(MAXM / 256, N_IMG), dim3(256), 0, stream,
                       cand, cnt, box_reg, anchors, oboxg, bboxg, scg, clsg);
    hipLaunchKernelGGL(mask_kernel, dim3(17, N_IMG), dim3(256), 0, stream,
                       oboxg, maskT, tdiag);
    hipLaunchKernelGGL(sweep_out_kernel, dim3(N_IMG), dim3(1024), 0, stream,
                       bboxg, scg, clsg, tdiag, maskT, out);
}